// Round 15
// baseline (825.108 us; speedup 1.0000x reference)
//
#include <hip/hip_runtime.h>

using bf16x8 = __attribute__((ext_vector_type(8))) __bf16;
using bf16x4 = __attribute__((ext_vector_type(4))) __bf16;
using f32x4  = __attribute__((ext_vector_type(4))) float;

#define MN    150000
#define NEDGE 300000
#define NG    6000
#define NSCAN 586   // ceil(MN/256)

// ---------------- dual-dtype helpers ----------------
// flags[0]=1 -> float tensors are fp32 (else bf16)
// flags[1]=1 -> edge_index is int64 (else int32)
// flags[2]=1 -> batch is int64 (else int32)
__device__ __forceinline__ float loadF(const void* p, size_t i, int f32) {
    return f32 ? ((const float*)p)[i] : (float)((const __bf16*)p)[i];
}
__device__ __forceinline__ int loadI(const int* p, size_t i, int i64) {
    return i64 ? p[2 * i] : p[i];
}

// ---------------- dtype probe ----------------
__global__ void k_probe(const void* W1a, const int* ei, const int* batch, int* flags) {
    __shared__ int s_f32, s_einz, s_bnz;
    if (threadIdx.x == 0) { s_f32 = 0; s_einz = 0; s_bnz = 0; }
    __syncthreads();
    const unsigned short* w = (const unsigned short*)W1a;
    for (int i = threadIdx.x; i < 1792; i += 256) {
        int e = (w[i] >> 7) & 0xFF;
        if (e >= 0xF0) s_f32 = 1;   // impossible for genuine |w|<=0.38 bf16
    }
    for (int i = threadIdx.x; i < 2048; i += 256)
        if (ei[2 * i + 1] != 0) s_einz = 1;
    for (int i = threadIdx.x; i < 2048; i += 256)
        if (batch[75000 + 2 * i + 1] != 0) s_bnz = 1;
    __syncthreads();
    if (threadIdx.x == 0) {
        flags[0] = s_f32;
        flags[1] = s_einz ? 0 : 1;
        flags[2] = s_bnz ? 0 : 1;
    }
}

// ---------------- small utility kernels ----------------
__global__ void k_zero_i32(int* p, int n) {
    int i = blockIdx.x * 256 + threadIdx.x;
    if (i < n) p[i] = 0;
}
__global__ void k_zero_f32(float* p, int n) {
    int i = blockIdx.x * 256 + threadIdx.x;
    if (i < n) p[i] = 0.f;
}

// all 7 weight transposes in one launch: Wt[j][n][k] = W[j][k][n]
__global__ void k_cvtWT(const void* W0, const void* W1, const void* W2, const void* W3,
                        const void* W4, const void* W5, const void* W6,
                        __bf16* __restrict__ Wt, const int* __restrict__ flags) {
    int j = blockIdx.x >> 8;
    int n = blockIdx.x & 255, k = threadIdx.x;
    const void* Ws[7] = {W0, W1, W2, W3, W4, W5, W6};
    Wt[(size_t)j * 65536 + (size_t)n * 256 + k] = (__bf16)loadF(Ws[j], (size_t)k * 256 + n, flags[0]);
}

// ---------------- CSR build (by dst) ----------------
__global__ void k_deg(const int* __restrict__ ei, int* __restrict__ cnt, int nE,
                      const int* __restrict__ flags) {
    int e = blockIdx.x * 256 + threadIdx.x;
    if (e >= nE) return;
    int i64 = flags[1];
    int d = loadI(ei, (size_t)nE + e, i64);
    if ((unsigned)d >= (unsigned)MN) d = 0;
    atomicAdd(&cnt[d], 1);
}
__global__ void k_blksum(const int* __restrict__ cnt, int* __restrict__ bsum, int n) {
    __shared__ int s[256];
    int t = threadIdx.x;
    int i = blockIdx.x * 256 + t;
    s[t] = (i < n) ? cnt[i] : 0;
    __syncthreads();
    for (int o = 128; o > 0; o >>= 1) {
        if (t < o) s[t] += s[t + o];
        __syncthreads();
    }
    if (t == 0) bsum[blockIdx.x] = s[0];
}
__global__ void k_scan1(const int* __restrict__ bsum, int* __restrict__ bbase, int nb) {
    if (threadIdx.x == 0 && blockIdx.x == 0) {
        int a = 0;
        for (int i = 0; i < nb; ++i) { bbase[i] = a; a += bsum[i]; }
    }
}
__global__ void k_blkscan(const int* __restrict__ cnt, const int* __restrict__ bbase,
                          int* __restrict__ offs, int n) {
    __shared__ int s[256];
    int t = threadIdx.x;
    int i = blockIdx.x * 256 + t;
    int v = (i < n) ? cnt[i] : 0;
    s[t] = v;
    __syncthreads();
    for (int o = 1; o < 256; o <<= 1) {
        int x = (t >= o) ? s[t - o] : 0;
        __syncthreads();
        s[t] += x;
        __syncthreads();
    }
    if (i < n) offs[i] = bbase[blockIdx.x] + s[t] - v;
}
__global__ void k_fill(const int* __restrict__ ei, const int* __restrict__ offs,
                       int* __restrict__ cur, int* __restrict__ elist, int nE,
                       const int* __restrict__ flags) {
    int e = blockIdx.x * 256 + threadIdx.x;
    if (e >= nE) return;
    int i64 = flags[1];
    int s = loadI(ei, (size_t)e, i64);
    int d = loadI(ei, (size_t)nE + e, i64);
    if ((unsigned)s >= (unsigned)MN) s = 0;
    if ((unsigned)d >= (unsigned)MN) d = 0;
    int pos = offs[d] + atomicAdd(&cur[d], 1);
    // guard vs rocprof-replay corrupting stateful atomics (timed runs rebuild cleanly)
    if ((unsigned)pos < (unsigned)NEDGE) elist[pos] = s;
}

// ---------------- layer 1 lite: agg7 only -> AGG7 (fp32, padded to 8) ----------------
__global__ __launch_bounds__(256) void k_l1lite(
    const void* __restrict__ x, const int* __restrict__ offs,
    const int* __restrict__ deg, const int* __restrict__ elist,
    float* __restrict__ agg7, const int* __restrict__ flags, int M_) {
    int f32 = flags[0];
    int t = threadIdx.x;
    int v = blockIdx.x * 32 + (t >> 3);
    int j = t & 7;
    if (v >= M_ || j >= 7) return;
    float s = loadF(x, (size_t)v * 7 + j, f32);
    int b = offs[v], d = min(deg[v], 1024);
    for (int e = 0; e < d; ++e) {
        int u = elist[b + e];
        if ((unsigned)u >= (unsigned)MN) u = 0;
        s += loadF(x, (size_t)u * 7 + j, f32);
    }
    agg7[(size_t)v * 8 + j] = s;
}

// ---------------- aggregation: X[v] = h[v] + sum_{dst(e)=v} h[src(e)] ----------------
// pair-row gather: half-wave (32 lanes x 16B) covers one full 512B row; 2 pairs batched.
__global__ __launch_bounds__(256) void k_agg(const __bf16* __restrict__ H, __bf16* __restrict__ X,
                                             const int* __restrict__ offs, const int* __restrict__ deg,
                                             const int* __restrict__ elist, int M_) {
    int wave = threadIdx.x >> 6;
    int lane = threadIdx.x & 63;
    int half = lane >> 5;        // 0/1 -> which row of the pair
    int c = (lane & 31) * 8;     // col base (bf16x8)
    int r0 = blockIdx.x * 16 + wave * 4;
    if (r0 >= M_) return;

    int myrow[2], myoff[2], mydeg[2];
    float acc[2][8];
#pragma unroll
    for (int pp = 0; pp < 2; ++pp) {
        int r = r0 + pp * 2 + half;
        myrow[pp] = r;
        myoff[pp] = offs[r];
        mydeg[pp] = min(deg[r], 1024);
        bf16x8 a = *(const bf16x8*)(H + (size_t)r * 256 + c);
#pragma unroll
        for (int j = 0; j < 8; ++j) acc[pp][j] = (float)a[j];
    }
    int maxd = 0;
#pragma unroll
    for (int i = 0; i < 4; ++i) maxd = max(maxd, min(deg[r0 + i], 1024));

    for (int e = 0; e < maxd; ++e) {
        bf16x8 nb[2];
#pragma unroll
        for (int pp = 0; pp < 2; ++pp) {
            if (e < mydeg[pp]) {
                int u = elist[myoff[pp] + e];
                if ((unsigned)u >= (unsigned)MN) u = 0;
                nb[pp] = *(const bf16x8*)(H + (size_t)u * 256 + c);
            }
        }
#pragma unroll
        for (int pp = 0; pp < 2; ++pp) {
            if (e < mydeg[pp]) {
#pragma unroll
                for (int j = 0; j < 8; ++j) acc[pp][j] += (float)nb[pp][j];
            }
        }
    }
#pragma unroll
    for (int pp = 0; pp < 2; ++pp) {
        bf16x8 o;
#pragma unroll
        for (int j = 0; j < 8; ++j) o[j] = (__bf16)acc[pp][j];
        *(bf16x8*)(X + (size_t)myrow[pp] * 256 + c) = o;
    }
}

// ---------------- MFMA GEMM core, 128-row tile ----------------
__device__ __forceinline__ void gemm_core128(const __bf16* lA, const __bf16* __restrict__ WT,
                                             int n0, int lm, int lq, f32x4 acc[4][8]) {
    const __bf16* wp = WT + (size_t)(n0 + lm) * 256 + lq * 8;
    bf16x8 wf[4], wn[4];
#pragma unroll
    for (int ci = 0; ci < 4; ++ci)
        wf[ci] = *(const bf16x8*)(wp + ci * 16 * 256);
#pragma unroll
    for (int kt = 0; kt < 8; ++kt) {
        if (kt < 7) {
#pragma unroll
            for (int ci = 0; ci < 4; ++ci)
                wn[ci] = *(const bf16x8*)(wp + ci * 16 * 256 + (kt + 1) * 32);
        }
        int sw = (((kt * 4 + lq) ^ (lm & 7)) << 3);
        bf16x8 xf[8];
#pragma unroll
        for (int mi = 0; mi < 8; ++mi)
            xf[mi] = *(const bf16x8*)(lA + (mi * 16 + lm) * 256 + sw);
#pragma unroll
        for (int ci = 0; ci < 4; ++ci)
#pragma unroll
            for (int mi = 0; mi < 8; ++mi)
                acc[ci][mi] = __builtin_amdgcn_mfma_f32_16x16x32_bf16(
                    wf[ci], xf[mi], acc[ci][mi], 0, 0, 0);
#pragma unroll
        for (int ci = 0; ci < 4; ++ci) wf[ci] = wn[ci];
    }
}

// stage 128 rows of X into swizzled LDS (2 threads/row).
// NON-TEMPORAL loads: X is read-once here (next access overwrites), so keep the
// streamed 10 MB/XCD from thrashing the L2 and evicting the 896 KB weight set.
__device__ __forceinline__ void stage128(const __bf16* __restrict__ X, __bf16* lA,
                                         int bm, int t, int M_) {
    int r = t >> 1;
    int gr = bm + r;
    if (gr >= M_) gr = M_ - 1;
    const __bf16* src = X + (size_t)gr * 256;
    int c0 = (t & 1) * 16;
#pragma unroll
    for (int j = 0; j < 16; ++j) {
        int c = c0 + j;
        bf16x8 v = __builtin_nontemporal_load((const bf16x8*)(src + c * 8));
        *(bf16x8*)(lA + r * 256 + ((c ^ (r & 7)) << 3)) = v;
    }
}

// epilogue helper: write acc tile (relu(acc+bias)) into swizzled LDS
__device__ __forceinline__ void epi_to_lds(__bf16* lA, f32x4 acc[4][8], const void* bias,
                                           int n0, int lm, int lq, int f32) {
#pragma unroll
    for (int ci = 0; ci < 4; ++ci) {
        int n4 = n0 + ci * 16 + lq * 4;
        float b0 = loadF(bias, n4 + 0, f32), b1 = loadF(bias, n4 + 1, f32);
        float b2 = loadF(bias, n4 + 2, f32), b3 = loadF(bias, n4 + 3, f32);
#pragma unroll
        for (int mi = 0; mi < 8; ++mi) {
            int m = mi * 16 + lm;
            f32x4 a = acc[ci][mi];
            bf16x4 v;
            v[0] = (__bf16)fmaxf(a[0] + b0, 0.f);
            v[1] = (__bf16)fmaxf(a[1] + b1, 0.f);
            v[2] = (__bf16)fmaxf(a[2] + b2, 0.f);
            v[3] = (__bf16)fmaxf(a[3] + b3, 0.f);
            *(bf16x4*)(lA + m * 256 + (((n4 >> 3) ^ (m & 7)) << 3) + (n4 & 7)) = v;
        }
    }
}

// epilogue helper: full-line stores from swizzled LDS to Y (normal caching:
// Y is re-read randomly by the next k_agg, keep it in L2/L3)
__device__ __forceinline__ void lds_to_global(const __bf16* lA, __bf16* __restrict__ Y,
                                              int bm, int w, int lane, int M_) {
    int half = lane >> 5;
    int cc = lane & 31;
#pragma unroll
    for (int it = 0; it < 16; ++it) {
        int r = w * 32 + it * 2 + half;
        int gm = bm + r;
        if (gm < M_) {
            bf16x8 v = *(const bf16x8*)(lA + r * 256 + ((cc ^ (r & 7)) << 3));
            *(bf16x8*)(Y + (size_t)gm * 256 + cc * 8) = v;
        }
    }
}

// ---------------- fused GIN MLP: Y = relu( relu(X@Wa+ba) @ Wb + bb ) ----------------
__global__ __launch_bounds__(256, 2) void k_gin_mlp(
    const __bf16* __restrict__ X, const __bf16* __restrict__ WaT, const void* __restrict__ ba,
    const __bf16* __restrict__ WbT, const void* __restrict__ bb,
    __bf16* __restrict__ Y, int M_, const int* __restrict__ flags) {
    __shared__ __align__(16) __bf16 lA[128 * 256];
    int t = threadIdx.x;
    int f32 = flags[0];
    int bm = blockIdx.x * 128;
    int w = t >> 6, lane = t & 63, lm = lane & 15, lq = lane >> 4;
    int n0 = w * 64;

    stage128(X, lA, bm, t, M_);
    __syncthreads();

    {
        f32x4 acc[4][8] = {};
        gemm_core128(lA, WaT, n0, lm, lq, acc);
        __syncthreads();   // all lA reads done; safe to overwrite with mid
        epi_to_lds(lA, acc, ba, n0, lm, lq, f32);
    }
    __syncthreads();

    f32x4 acc2[4][8] = {};
    gemm_core128(lA, WbT, n0, lm, lq, acc2);
    __syncthreads();       // all lA reads done; safe to overwrite with result
    epi_to_lds(lA, acc2, bb, n0, lm, lq, f32);
    __syncthreads();
    lds_to_global(lA, Y, bm, w, lane, M_);
}

// ---------------- layer-1 GEMM: staging computes 7->256 linear from AGG7 ----------------
__global__ __launch_bounds__(256, 2) void k_gemm1(
    const float* __restrict__ agg7, const void* __restrict__ W1a, const void* __restrict__ b1a,
    const __bf16* __restrict__ WT, const void* __restrict__ bias,
    __bf16* __restrict__ Y, int M_, const int* __restrict__ flags) {
    __shared__ __align__(16) __bf16 lA[128 * 256];
    __shared__ float sW[7 * 256];
    __shared__ float sB[256];
    int t = threadIdx.x;
    int f32 = flags[0];
    int bm = blockIdx.x * 128;
    int w = t >> 6, lane = t & 63, lm = lane & 15, lq = lane >> 4;
    int n0 = w * 64;

    sB[t] = loadF(b1a, t, f32);
#pragma unroll
    for (int k = 0; k < 7; ++k) sW[k * 256 + t] = loadF(W1a, (size_t)k * 256 + t, f32);
    __syncthreads();

    {
        int r = t >> 1;
        int gr = bm + r;
        if (gr >= M_) gr = M_ - 1;
        float a[7];
#pragma unroll
        for (int k = 0; k < 7; ++k) a[k] = agg7[(size_t)gr * 8 + k];
        int c0 = (t & 1) * 128;
#pragma unroll
        for (int s8 = 0; s8 < 16; ++s8) {
            bf16x8 o;
#pragma unroll
            for (int j = 0; j < 8; ++j) {
                int cc = c0 + s8 * 8 + j;
                float v = sB[cc];
#pragma unroll
                for (int k = 0; k < 7; ++k) v = fmaf(a[k], sW[k * 256 + cc], v);
                o[j] = (__bf16)fmaxf(v, 0.f);
            }
            int ch = (c0 >> 3) + s8;
            *(bf16x8*)(lA + r * 256 + ((ch ^ (r & 7)) << 3)) = o;
        }
    }
    __syncthreads();

    f32x4 acc[4][8] = {};
    gemm_core128(lA, WT, n0, lm, lq, acc);
    __syncthreads();
    epi_to_lds(lA, acc, bias, n0, lm, lq, f32);
    __syncthreads();
    lds_to_global(lA, Y, bm, w, lane, M_);
}

// ---------------- mean pool (batch sorted) ----------------
__global__ void k_pool(const __bf16* __restrict__ h, const int* __restrict__ batch,
                       float* __restrict__ pool, float* __restrict__ cnt, int M_,
                       const int* __restrict__ flags) {
    int f = threadIdx.x;
    int base = blockIdx.x * 32;
    if (base >= M_) return;
    int i64 = flags[2];
    int end = min(base + 32, M_);
    int g = loadI(batch, base, i64);
    if ((unsigned)g >= (unsigned)NG) g = 0;
    float acc = 0.f;
    int run = 0;
    for (int m = base; m < end; ++m) {
        int bm = loadI(batch, m, i64);
        if ((unsigned)bm >= (unsigned)NG) bm = 0;
        if (bm != g) {
            atomicAdd(&pool[(size_t)g * 256 + f], acc);
            if (f == 0) atomicAdd(&cnt[g], (float)run);
            g = bm; acc = 0.f; run = 0;
        }
        acc += (float)h[(size_t)m * 256 + f];
        run++;
    }
    atomicAdd(&pool[(size_t)g * 256 + f], acc);
    if (f == 0) atomicAdd(&cnt[g], (float)run);
}

// ---------------- head ----------------
__global__ void k_head1(const float* __restrict__ pool, const float* __restrict__ cnt,
                        const void* __restrict__ Wh1, const void* __restrict__ bh1,
                        float* __restrict__ hid, const int* __restrict__ flags) {
    int g = blockIdx.x, n = threadIdx.x;   // 128 threads
    int f32 = flags[0];
    __shared__ float p[256];
    float inv = 1.0f / fmaxf(cnt[g], 1.0f);
    for (int k = n; k < 256; k += 128) p[k] = pool[(size_t)g * 256 + k] * inv;
    __syncthreads();
    float s = loadF(bh1, n, f32);
    for (int k = 0; k < 256; ++k) s = fmaf(p[k], loadF(Wh1, (size_t)k * 128 + n, f32), s);
    hid[(size_t)g * 128 + n] = fmaxf(s, 0.f);
}

__global__ void k_head2(const float* __restrict__ hid, const void* __restrict__ Wh2,
                        const void* __restrict__ bh2, void* __restrict__ outv, int n,
                        const int* __restrict__ flags) {
    int t = blockIdx.x * 256 + threadIdx.x;
    if (t >= n) return;
    int f32 = flags[0];
    int g = t / 3, o = t % 3;
    float s = loadF(bh2, o, f32);
    for (int k = 0; k < 128; ++k)
        s = fmaf(hid[(size_t)g * 128 + k], loadF(Wh2, (size_t)k * 3 + o, f32), s);
    if (f32) ((float*)outv)[t] = s;
    else     ((__bf16*)outv)[t] = (__bf16)s;
}

// ---------------- launch ----------------
extern "C" void kernel_launch(void* const* d_in, const int* in_sizes, int n_in,
                              void* d_out, int out_size, void* d_ws, size_t ws_size,
                              hipStream_t stream) {
    const void* x     = d_in[0];
    const int*  ei    = (const int*)d_in[1];
    const int*  batch = (const int*)d_in[2];
    const void *W[4][2], *b[4][2];
    for (int l = 0; l < 4; ++l) {
        W[l][0] = d_in[3 + 4 * l];
        b[l][0] = d_in[4 + 4 * l];
        W[l][1] = d_in[5 + 4 * l];
        b[l][1] = d_in[6 + 4 * l];
    }
    const void* Wh1 = d_in[19];
    const void* bh1 = d_in[20];
    const void* Wh2 = d_in[21];
    const void* bh2 = d_in[22];

    char* p = (char*)d_ws;
    auto alloc = [&](size_t bytes) -> char* {
        char* r = p;
        p += (bytes + 255) & ~(size_t)255;
        return r;
    };
    __bf16* B1    = (__bf16*)alloc((size_t)MN * 256 * 2);   // 76.8 MB
    __bf16* B2    = (__bf16*)alloc((size_t)MN * 256 * 2);   // 76.8 MB
    __bf16* WT    = (__bf16*)alloc((size_t)7 * 256 * 256 * 2);
    float*  AGG7  = (float*)alloc((size_t)MN * 8 * 4);      // 4.8 MB
    int*    offs  = (int*)alloc((size_t)MN * 4);
    int*    cnt   = (int*)alloc((size_t)MN * 4);
    int*    elist = (int*)alloc((size_t)NEDGE * 4);
    int*    bsum  = (int*)alloc((size_t)NSCAN * 4);
    int*    bbase = (int*)alloc((size_t)NSCAN * 4);
    float*  POOL  = (float*)alloc((size_t)NG * 256 * 4);    // CNTF contiguous after
    float*  CNTF  = (float*)alloc((size_t)NG * 4);
    float*  HD    = (float*)alloc((size_t)NG * 128 * 4);
    int*    flags = (int*)alloc(64);

    // ---- dtype probe ----
    k_probe<<<1, 256, 0, stream>>>(W[0][0], ei, batch, flags);

    // ---- transposed bf16 weights [n][k]: W1b, W2a, W2b, W3a, W3b, W4a, W4b ----
    k_cvtWT<<<7 * 256, 256, 0, stream>>>(W[0][1], W[1][0], W[1][1], W[2][0], W[2][1],
                                         W[3][0], W[3][1], WT, flags);

    // ---- CSR build (by dst) ----
    k_zero_i32<<<NSCAN, 256, 0, stream>>>(cnt, MN);
    k_deg<<<(NEDGE + 255) / 256, 256, 0, stream>>>(ei, cnt, NEDGE, flags);
    k_blksum<<<NSCAN, 256, 0, stream>>>(cnt, bsum, MN);
    k_scan1<<<1, 64, 0, stream>>>(bsum, bbase, NSCAN);
    k_blkscan<<<NSCAN, 256, 0, stream>>>(cnt, bbase, offs, MN);
    k_zero_i32<<<NSCAN, 256, 0, stream>>>(cnt, MN);   // cursor
    k_fill<<<(NEDGE + 255) / 256, 256, 0, stream>>>(ei, offs, cnt, elist, NEDGE, flags);
    // after k_fill, cnt[v] == degree(v)

    // ---- zero pool accumulators ----
    k_zero_f32<<<(NG * 257 + 255) / 256, 256, 0, stream>>>(POOL, NG * 256 + NG); // POOL+CNTF

    int gblocks = (MN + 127) / 128;
    int ablocks = (MN + 15) / 16;

    // ---- layer 1: gather-7 + (lin1 fused into gemm1 staging) ----
    k_l1lite<<<(MN + 31) / 32, 256, 0, stream>>>(x, offs, cnt, elist, AGG7, flags, MN);
    k_gemm1<<<gblocks, 256, 0, stream>>>(AGG7, W[0][0], b[0][0], WT /*W1b^T*/, b[0][1],
                                         B1, MN, flags);

    // ---- layers 2..4 (split: agg then MLP) ----
    for (int l = 1; l < 4; ++l) {
        k_agg<<<ablocks, 256, 0, stream>>>(B1, B2, offs, cnt, elist, MN);
        const __bf16* WaT = WT + (size_t)(1 + 2 * (l - 1)) * 65536;
        const __bf16* WbT = WT + (size_t)(2 + 2 * (l - 1)) * 65536;
        k_gin_mlp<<<gblocks, 256, 0, stream>>>(B2, WaT, b[l][0], WbT, b[l][1], B1, MN, flags);
    }

    // ---- pool + head ----
    k_pool<<<(MN + 31) / 32, 256, 0, stream>>>(B1, batch, POOL, CNTF, MN, flags);
    k_head1<<<NG, 128, 0, stream>>>(POOL, CNTF, Wh1, bh1, HD, flags);
    k_head2<<<(NG * 3 + 255) / 256, 256, 0, stream>>>(HD, Wh2, bh2, d_out, NG * 3, flags);
}

// Round 16
// 670.703 us; speedup vs baseline: 1.2302x; 1.2302x over previous
//
#include <hip/hip_runtime.h>

using bf16x8 = __attribute__((ext_vector_type(8))) __bf16;
using bf16x4 = __attribute__((ext_vector_type(4))) __bf16;
using f32x4  = __attribute__((ext_vector_type(4))) float;

#define MN    150000
#define NEDGE 300000
#define NG    6000
#define NSCAN 586   // ceil(MN/256)

// ---------------- dual-dtype helpers ----------------
// flags[0]=1 -> float tensors are fp32 (else bf16)
// flags[1]=1 -> edge_index is int64 (else int32)
// flags[2]=1 -> batch is int64 (else int32)
__device__ __forceinline__ float loadF(const void* p, size_t i, int f32) {
    return f32 ? ((const float*)p)[i] : (float)((const __bf16*)p)[i];
}
__device__ __forceinline__ int loadI(const int* p, size_t i, int i64) {
    return i64 ? p[2 * i] : p[i];
}

// ---------------- dtype probe ----------------
__global__ void k_probe(const void* W1a, const int* ei, const int* batch, int* flags) {
    __shared__ int s_f32, s_einz, s_bnz;
    if (threadIdx.x == 0) { s_f32 = 0; s_einz = 0; s_bnz = 0; }
    __syncthreads();
    const unsigned short* w = (const unsigned short*)W1a;
    for (int i = threadIdx.x; i < 1792; i += 256) {
        int e = (w[i] >> 7) & 0xFF;
        if (e >= 0xF0) s_f32 = 1;   // impossible for genuine |w|<=0.38 bf16
    }
    for (int i = threadIdx.x; i < 2048; i += 256)
        if (ei[2 * i + 1] != 0) s_einz = 1;
    for (int i = threadIdx.x; i < 2048; i += 256)
        if (batch[75000 + 2 * i + 1] != 0) s_bnz = 1;
    __syncthreads();
    if (threadIdx.x == 0) {
        flags[0] = s_f32;
        flags[1] = s_einz ? 0 : 1;
        flags[2] = s_bnz ? 0 : 1;
    }
}

// ---------------- small utility kernels ----------------
__global__ void k_zero_i32(int* p, int n) {
    int i = blockIdx.x * 256 + threadIdx.x;
    if (i < n) p[i] = 0;
}
__global__ void k_zero_f32(float* p, int n) {
    int i = blockIdx.x * 256 + threadIdx.x;
    if (i < n) p[i] = 0.f;
}

// all 7 weight transposes in one launch: Wt[j][n][k] = W[j][k][n]
__global__ void k_cvtWT(const void* W0, const void* W1, const void* W2, const void* W3,
                        const void* W4, const void* W5, const void* W6,
                        __bf16* __restrict__ Wt, const int* __restrict__ flags) {
    int j = blockIdx.x >> 8;
    int n = blockIdx.x & 255, k = threadIdx.x;
    const void* Ws[7] = {W0, W1, W2, W3, W4, W5, W6};
    Wt[(size_t)j * 65536 + (size_t)n * 256 + k] = (__bf16)loadF(Ws[j], (size_t)k * 256 + n, flags[0]);
}

// ---------------- CSR build (by dst) ----------------
__global__ void k_deg(const int* __restrict__ ei, int* __restrict__ cnt, int nE,
                      const int* __restrict__ flags) {
    int e = blockIdx.x * 256 + threadIdx.x;
    if (e >= nE) return;
    int i64 = flags[1];
    int d = loadI(ei, (size_t)nE + e, i64);
    if ((unsigned)d >= (unsigned)MN) d = 0;
    atomicAdd(&cnt[d], 1);
}
__global__ void k_blksum(const int* __restrict__ cnt, int* __restrict__ bsum, int n) {
    __shared__ int s[256];
    int t = threadIdx.x;
    int i = blockIdx.x * 256 + t;
    s[t] = (i < n) ? cnt[i] : 0;
    __syncthreads();
    for (int o = 128; o > 0; o >>= 1) {
        if (t < o) s[t] += s[t + o];
        __syncthreads();
    }
    if (t == 0) bsum[blockIdx.x] = s[0];
}
// parallel block-base scan: 1024 threads, Hillis-Steele over NSCAN elements
__global__ __launch_bounds__(1024) void k_scanb(const int* __restrict__ bsum,
                                                int* __restrict__ bbase, int nb) {
    __shared__ int s[1024];
    int t = threadIdx.x;
    int v = (t < nb) ? bsum[t] : 0;
    s[t] = v;
    __syncthreads();
#pragma unroll
    for (int o = 1; o < 1024; o <<= 1) {
        int x = (t >= o) ? s[t - o] : 0;
        __syncthreads();
        s[t] += x;
        __syncthreads();
    }
    if (t < nb) bbase[t] = s[t] - v;   // exclusive
}
__global__ void k_blkscan(const int* __restrict__ cnt, const int* __restrict__ bbase,
                          int* __restrict__ offs, int n) {
    __shared__ int s[256];
    int t = threadIdx.x;
    int i = blockIdx.x * 256 + t;
    int v = (i < n) ? cnt[i] : 0;
    s[t] = v;
    __syncthreads();
    for (int o = 1; o < 256; o <<= 1) {
        int x = (t >= o) ? s[t - o] : 0;
        __syncthreads();
        s[t] += x;
        __syncthreads();
    }
    if (i < n) offs[i] = bbase[blockIdx.x] + s[t] - v;
}
__global__ void k_fill(const int* __restrict__ ei, const int* __restrict__ offs,
                       int* __restrict__ cur, int* __restrict__ elist, int nE,
                       const int* __restrict__ flags) {
    int e = blockIdx.x * 256 + threadIdx.x;
    if (e >= nE) return;
    int i64 = flags[1];
    int s = loadI(ei, (size_t)e, i64);
    int d = loadI(ei, (size_t)nE + e, i64);
    if ((unsigned)s >= (unsigned)MN) s = 0;
    if ((unsigned)d >= (unsigned)MN) d = 0;
    int pos = offs[d] + atomicAdd(&cur[d], 1);
    // guard vs rocprof-replay corrupting stateful atomics (timed runs rebuild cleanly)
    if ((unsigned)pos < (unsigned)NEDGE) elist[pos] = s;
}

// ---------------- layer 1 lite: agg7 only -> AGG7 (fp32, padded to 8) ----------------
__global__ __launch_bounds__(256) void k_l1lite(
    const void* __restrict__ x, const int* __restrict__ offs,
    const int* __restrict__ deg, const int* __restrict__ elist,
    float* __restrict__ agg7, const int* __restrict__ flags, int M_) {
    int f32 = flags[0];
    int t = threadIdx.x;
    int v = blockIdx.x * 32 + (t >> 3);
    int j = t & 7;
    if (v >= M_ || j >= 7) return;
    float s = loadF(x, (size_t)v * 7 + j, f32);
    int b = offs[v], d = min(deg[v], 1024);
    for (int e = 0; e < d; ++e) {
        int u = elist[b + e];
        if ((unsigned)u >= (unsigned)MN) u = 0;
        s += loadF(x, (size_t)u * 7 + j, f32);
    }
    agg7[(size_t)v * 8 + j] = s;
}

// ---------------- aggregation: X[v] = h[v] + sum_{dst(e)=v} h[src(e)] ----------------
// pair-row gather: half-wave (32 lanes x 16B) covers one full 512B row; 2 pairs batched.
__global__ __launch_bounds__(256) void k_agg(const __bf16* __restrict__ H, __bf16* __restrict__ X,
                                             const int* __restrict__ offs, const int* __restrict__ deg,
                                             const int* __restrict__ elist, int M_) {
    int wave = threadIdx.x >> 6;
    int lane = threadIdx.x & 63;
    int half = lane >> 5;        // 0/1 -> which row of the pair
    int c = (lane & 31) * 8;     // col base (bf16x8)
    int r0 = blockIdx.x * 16 + wave * 4;
    if (r0 >= M_) return;

    int myrow[2], myoff[2], mydeg[2];
    float acc[2][8];
#pragma unroll
    for (int pp = 0; pp < 2; ++pp) {
        int r = r0 + pp * 2 + half;
        myrow[pp] = r;
        myoff[pp] = offs[r];
        mydeg[pp] = min(deg[r], 1024);
        bf16x8 a = *(const bf16x8*)(H + (size_t)r * 256 + c);
#pragma unroll
        for (int j = 0; j < 8; ++j) acc[pp][j] = (float)a[j];
    }
    int maxd = 0;
#pragma unroll
    for (int i = 0; i < 4; ++i) maxd = max(maxd, min(deg[r0 + i], 1024));

    for (int e = 0; e < maxd; ++e) {
        bf16x8 nb[2];
#pragma unroll
        for (int pp = 0; pp < 2; ++pp) {
            if (e < mydeg[pp]) {
                int u = elist[myoff[pp] + e];
                if ((unsigned)u >= (unsigned)MN) u = 0;
                nb[pp] = *(const bf16x8*)(H + (size_t)u * 256 + c);
            }
        }
#pragma unroll
        for (int pp = 0; pp < 2; ++pp) {
            if (e < mydeg[pp]) {
#pragma unroll
                for (int j = 0; j < 8; ++j) acc[pp][j] += (float)nb[pp][j];
            }
        }
    }
#pragma unroll
    for (int pp = 0; pp < 2; ++pp) {
        bf16x8 o;
#pragma unroll
        for (int j = 0; j < 8; ++j) o[j] = (__bf16)acc[pp][j];
        *(bf16x8*)(X + (size_t)myrow[pp] * 256 + c) = o;
    }
}

// ---------------- MFMA GEMM core, 128-row tile ----------------
__device__ __forceinline__ void gemm_core128(const __bf16* lA, const __bf16* __restrict__ WT,
                                             int n0, int lm, int lq, f32x4 acc[4][8]) {
    const __bf16* wp = WT + (size_t)(n0 + lm) * 256 + lq * 8;
    bf16x8 wf[4], wn[4];
#pragma unroll
    for (int ci = 0; ci < 4; ++ci)
        wf[ci] = *(const bf16x8*)(wp + ci * 16 * 256);
#pragma unroll
    for (int kt = 0; kt < 8; ++kt) {
        if (kt < 7) {
#pragma unroll
            for (int ci = 0; ci < 4; ++ci)
                wn[ci] = *(const bf16x8*)(wp + ci * 16 * 256 + (kt + 1) * 32);
        }
        int sw = (((kt * 4 + lq) ^ (lm & 7)) << 3);
        bf16x8 xf[8];
#pragma unroll
        for (int mi = 0; mi < 8; ++mi)
            xf[mi] = *(const bf16x8*)(lA + (mi * 16 + lm) * 256 + sw);
#pragma unroll
        for (int ci = 0; ci < 4; ++ci)
#pragma unroll
            for (int mi = 0; mi < 8; ++mi)
                acc[ci][mi] = __builtin_amdgcn_mfma_f32_16x16x32_bf16(
                    wf[ci], xf[mi], acc[ci][mi], 0, 0, 0);
#pragma unroll
        for (int ci = 0; ci < 4; ++ci) wf[ci] = wn[ci];
    }
}

// stage 128 rows of X (bf16 row-major 256) into swizzled LDS (2 threads/row)
// normal (cached) loads — NT variant measured +34 us/dispatch (round 15)
__device__ __forceinline__ void stage128(const __bf16* __restrict__ X, __bf16* lA,
                                         int bm, int t, int M_) {
    int r = t >> 1;
    int gr = bm + r;
    if (gr >= M_) gr = M_ - 1;
    const __bf16* src = X + (size_t)gr * 256;
    int c0 = (t & 1) * 16;
#pragma unroll
    for (int j = 0; j < 16; ++j) {
        int c = c0 + j;
        *(bf16x8*)(lA + r * 256 + ((c ^ (r & 7)) << 3)) = *(const bf16x8*)(src + c * 8);
    }
}

// epilogue helper: write acc tile (relu(acc+bias)) into swizzled LDS
__device__ __forceinline__ void epi_to_lds(__bf16* lA, f32x4 acc[4][8], const void* bias,
                                           int n0, int lm, int lq, int f32) {
#pragma unroll
    for (int ci = 0; ci < 4; ++ci) {
        int n4 = n0 + ci * 16 + lq * 4;
        float b0 = loadF(bias, n4 + 0, f32), b1 = loadF(bias, n4 + 1, f32);
        float b2 = loadF(bias, n4 + 2, f32), b3 = loadF(bias, n4 + 3, f32);
#pragma unroll
        for (int mi = 0; mi < 8; ++mi) {
            int m = mi * 16 + lm;
            f32x4 a = acc[ci][mi];
            bf16x4 v;
            v[0] = (__bf16)fmaxf(a[0] + b0, 0.f);
            v[1] = (__bf16)fmaxf(a[1] + b1, 0.f);
            v[2] = (__bf16)fmaxf(a[2] + b2, 0.f);
            v[3] = (__bf16)fmaxf(a[3] + b3, 0.f);
            *(bf16x4*)(lA + m * 256 + (((n4 >> 3) ^ (m & 7)) << 3) + (n4 & 7)) = v;
        }
    }
}

// epilogue helper: full-line stores from swizzled LDS to Y
__device__ __forceinline__ void lds_to_global(const __bf16* lA, __bf16* __restrict__ Y,
                                              int bm, int w, int lane, int M_) {
    int half = lane >> 5;
    int cc = lane & 31;
#pragma unroll
    for (int it = 0; it < 16; ++it) {
        int r = w * 32 + it * 2 + half;
        int gm = bm + r;
        if (gm < M_) {
            bf16x8 v = *(const bf16x8*)(lA + r * 256 + ((cc ^ (r & 7)) << 3));
            *(bf16x8*)(Y + (size_t)gm * 256 + cc * 8) = v;
        }
    }
}

// ---------------- fused GIN MLP: Y = relu( relu(X@Wa+ba) @ Wb + bb ) ----------------
__global__ __launch_bounds__(256, 2) void k_gin_mlp(
    const __bf16* __restrict__ X, const __bf16* __restrict__ WaT, const void* __restrict__ ba,
    const __bf16* __restrict__ WbT, const void* __restrict__ bb,
    __bf16* __restrict__ Y, int M_, const int* __restrict__ flags) {
    __shared__ __align__(16) __bf16 lA[128 * 256];
    int t = threadIdx.x;
    int f32 = flags[0];
    int bm = blockIdx.x * 128;
    int w = t >> 6, lane = t & 63, lm = lane & 15, lq = lane >> 4;
    int n0 = w * 64;

    stage128(X, lA, bm, t, M_);
    __syncthreads();

    {
        f32x4 acc[4][8] = {};
        gemm_core128(lA, WaT, n0, lm, lq, acc);
        __syncthreads();   // all lA reads done; safe to overwrite with mid
        epi_to_lds(lA, acc, ba, n0, lm, lq, f32);
    }
    __syncthreads();

    f32x4 acc2[4][8] = {};
    gemm_core128(lA, WbT, n0, lm, lq, acc2);
    __syncthreads();       // all lA reads done; safe to overwrite with result
    epi_to_lds(lA, acc2, bb, n0, lm, lq, f32);
    __syncthreads();
    lds_to_global(lA, Y, bm, w, lane, M_);
}

// ---------------- layer-1 GEMM: staging computes 7->256 linear from AGG7 ----------------
__global__ __launch_bounds__(256, 2) void k_gemm1(
    const float* __restrict__ agg7, const void* __restrict__ W1a, const void* __restrict__ b1a,
    const __bf16* __restrict__ WT, const void* __restrict__ bias,
    __bf16* __restrict__ Y, int M_, const int* __restrict__ flags) {
    __shared__ __align__(16) __bf16 lA[128 * 256];
    __shared__ float sW[7 * 256];
    __shared__ float sB[256];
    int t = threadIdx.x;
    int f32 = flags[0];
    int bm = blockIdx.x * 128;
    int w = t >> 6, lane = t & 63, lm = lane & 15, lq = lane >> 4;
    int n0 = w * 64;

    sB[t] = loadF(b1a, t, f32);
#pragma unroll
    for (int k = 0; k < 7; ++k) sW[k * 256 + t] = loadF(W1a, (size_t)k * 256 + t, f32);
    __syncthreads();

    {
        int r = t >> 1;
        int gr = bm + r;
        if (gr >= M_) gr = M_ - 1;
        float a[7];
#pragma unroll
        for (int k = 0; k < 7; ++k) a[k] = agg7[(size_t)gr * 8 + k];
        int c0 = (t & 1) * 128;
#pragma unroll
        for (int s8 = 0; s8 < 16; ++s8) {
            bf16x8 o;
#pragma unroll
            for (int j = 0; j < 8; ++j) {
                int cc = c0 + s8 * 8 + j;
                float v = sB[cc];
#pragma unroll
                for (int k = 0; k < 7; ++k) v = fmaf(a[k], sW[k * 256 + cc], v);
                o[j] = (__bf16)fmaxf(v, 0.f);
            }
            int ch = (c0 >> 3) + s8;
            *(bf16x8*)(lA + r * 256 + ((ch ^ (r & 7)) << 3)) = o;
        }
    }
    __syncthreads();

    f32x4 acc[4][8] = {};
    gemm_core128(lA, WT, n0, lm, lq, acc);
    __syncthreads();
    epi_to_lds(lA, acc, bias, n0, lm, lq, f32);
    __syncthreads();
    lds_to_global(lA, Y, bm, w, lane, M_);
}

// ---------------- mean pool (batch sorted) ----------------
__global__ void k_pool(const __bf16* __restrict__ h, const int* __restrict__ batch,
                       float* __restrict__ pool, float* __restrict__ cnt, int M_,
                       const int* __restrict__ flags) {
    int f = threadIdx.x;
    int base = blockIdx.x * 32;
    if (base >= M_) return;
    int i64 = flags[2];
    int end = min(base + 32, M_);
    int g = loadI(batch, base, i64);
    if ((unsigned)g >= (unsigned)NG) g = 0;
    float acc = 0.f;
    int run = 0;
    for (int m = base; m < end; ++m) {
        int bm = loadI(batch, m, i64);
        if ((unsigned)bm >= (unsigned)NG) bm = 0;
        if (bm != g) {
            atomicAdd(&pool[(size_t)g * 256 + f], acc);
            if (f == 0) atomicAdd(&cnt[g], (float)run);
            g = bm; acc = 0.f; run = 0;
        }
        acc += (float)h[(size_t)m * 256 + f];
        run++;
    }
    atomicAdd(&pool[(size_t)g * 256 + f], acc);
    if (f == 0) atomicAdd(&cnt[g], (float)run);
}

// ---------------- fused head: out[g][0..2] = relu(mean @ Wh1 + bh1) @ Wh2 + bh2 ----------------
__global__ void k_head(const float* __restrict__ pool, const float* __restrict__ cnt,
                       const void* __restrict__ Wh1, const void* __restrict__ bh1,
                       const void* __restrict__ Wh2, const void* __restrict__ bh2,
                       void* __restrict__ outv, const int* __restrict__ flags) {
    int g = blockIdx.x, n = threadIdx.x;   // 128 threads
    int f32 = flags[0];
    __shared__ float p[256];
    __shared__ float hid[128];
    float inv = 1.0f / fmaxf(cnt[g], 1.0f);
    for (int k = n; k < 256; k += 128) p[k] = pool[(size_t)g * 256 + k] * inv;
    __syncthreads();
    float s = loadF(bh1, n, f32);
    for (int k = 0; k < 256; ++k) s = fmaf(p[k], loadF(Wh1, (size_t)k * 128 + n, f32), s);
    hid[n] = fmaxf(s, 0.f);
    __syncthreads();
    if (n < 3) {
        float o = loadF(bh2, n, f32);
        for (int k = 0; k < 128; ++k)
            o = fmaf(hid[k], loadF(Wh2, (size_t)k * 3 + n, f32), o);
        if (f32) ((float*)outv)[(size_t)g * 3 + n] = o;
        else     ((__bf16*)outv)[(size_t)g * 3 + n] = (__bf16)o;
    }
}

// ---------------- launch ----------------
extern "C" void kernel_launch(void* const* d_in, const int* in_sizes, int n_in,
                              void* d_out, int out_size, void* d_ws, size_t ws_size,
                              hipStream_t stream) {
    const void* x     = d_in[0];
    const int*  ei    = (const int*)d_in[1];
    const int*  batch = (const int*)d_in[2];
    const void *W[4][2], *b[4][2];
    for (int l = 0; l < 4; ++l) {
        W[l][0] = d_in[3 + 4 * l];
        b[l][0] = d_in[4 + 4 * l];
        W[l][1] = d_in[5 + 4 * l];
        b[l][1] = d_in[6 + 4 * l];
    }
    const void* Wh1 = d_in[19];
    const void* bh1 = d_in[20];
    const void* Wh2 = d_in[21];
    const void* bh2 = d_in[22];

    char* p = (char*)d_ws;
    auto alloc = [&](size_t bytes) -> char* {
        char* r = p;
        p += (bytes + 255) & ~(size_t)255;
        return r;
    };
    __bf16* B1    = (__bf16*)alloc((size_t)MN * 256 * 2);   // 76.8 MB
    __bf16* B2    = (__bf16*)alloc((size_t)MN * 256 * 2);   // 76.8 MB
    __bf16* WT    = (__bf16*)alloc((size_t)7 * 256 * 256 * 2);
    float*  AGG7  = (float*)alloc((size_t)MN * 8 * 4);      // 4.8 MB
    int*    offs  = (int*)alloc((size_t)MN * 4);
    int*    cnt   = (int*)alloc((size_t)MN * 4);
    int*    elist = (int*)alloc((size_t)NEDGE * 4);
    int*    bsum  = (int*)alloc((size_t)NSCAN * 4);
    int*    bbase = (int*)alloc((size_t)NSCAN * 4);
    float*  POOL  = (float*)alloc((size_t)NG * 256 * 4);    // CNTF contiguous after
    float*  CNTF  = (float*)alloc((size_t)NG * 4);
    int*    flags = (int*)alloc(64);

    // ---- dtype probe ----
    k_probe<<<1, 256, 0, stream>>>(W[0][0], ei, batch, flags);

    // ---- transposed bf16 weights [n][k]: W1b, W2a, W2b, W3a, W3b, W4a, W4b ----
    k_cvtWT<<<7 * 256, 256, 0, stream>>>(W[0][1], W[1][0], W[1][1], W[2][0], W[2][1],
                                         W[3][0], W[3][1], WT, flags);

    // ---- CSR build (by dst) ----
    k_zero_i32<<<NSCAN, 256, 0, stream>>>(cnt, MN);
    k_deg<<<(NEDGE + 255) / 256, 256, 0, stream>>>(ei, cnt, NEDGE, flags);
    k_blksum<<<NSCAN, 256, 0, stream>>>(cnt, bsum, MN);
    k_scanb<<<1, 1024, 0, stream>>>(bsum, bbase, NSCAN);
    k_blkscan<<<NSCAN, 256, 0, stream>>>(cnt, bbase, offs, MN);
    k_zero_i32<<<NSCAN, 256, 0, stream>>>(cnt, MN);   // cursor
    k_fill<<<(NEDGE + 255) / 256, 256, 0, stream>>>(ei, offs, cnt, elist, NEDGE, flags);
    // after k_fill, cnt[v] == degree(v)

    // ---- zero pool accumulators ----
    k_zero_f32<<<(NG * 257 + 255) / 256, 256, 0, stream>>>(POOL, NG * 256 + NG); // POOL+CNTF

    int gblocks = (MN + 127) / 128;
    int ablocks = (MN + 15) / 16;

    // ---- layer 1: gather-7 + (lin1 fused into gemm1 staging) ----
    k_l1lite<<<(MN + 31) / 32, 256, 0, stream>>>(x, offs, cnt, elist, AGG7, flags, MN);
    k_gemm1<<<gblocks, 256, 0, stream>>>(AGG7, W[0][0], b[0][0], WT /*W1b^T*/, b[0][1],
                                         B1, MN, flags);

    // ---- layers 2..4 (split: agg then MLP) ----
    for (int l = 1; l < 4; ++l) {
        k_agg<<<ablocks, 256, 0, stream>>>(B1, B2, offs, cnt, elist, MN);
        const __bf16* WaT = WT + (size_t)(1 + 2 * (l - 1)) * 65536;
        const __bf16* WbT = WT + (size_t)(2 + 2 * (l - 1)) * 65536;
        k_gin_mlp<<<gblocks, 256, 0, stream>>>(B2, WaT, b[l][0], WbT, b[l][1], B1, MN, flags);
    }

    // ---- pool + fused head ----
    k_pool<<<(MN + 31) / 32, 256, 0, stream>>>(B1, batch, POOL, CNTF, MN, flags);
    k_head<<<NG, 128, 0, stream>>>(POOL, CNTF, Wh1, bh1, Wh2, bh2, d_out, flags);
}